// Round 5
// baseline (785.774 us; speedup 1.0000x reference)
//
#include <hip/hip_runtime.h>
#include <hip/hip_bf16.h>

// LSTM cell fused pipeline for MI355X (gfx950).
// B=4096, D=1024, H=2048, O=2048, all f32 in/out; GEMMs run in bf16 MFMA.
//
// Round-4 change: GEMMs moved from the m97 2-barrier 128x128 structure
// (measured 640 TF / MfmaUtil 27.7% on gates) to a counted-vmcnt pipelined
// 256x128 structure (T3+T4), with T2 LDS XOR-swizzle and T5 setprio:
//   - 8 waves (512 thr), per-wave 64x64 output (acc[4][4] of 16x16x32 MFMA)
//   - LDS ring of THREE K-tile slots (A[256][64] + B[128][64] bf16 = 48KB
//     per slot, 144 KB total -> 1 block/CU)
//   - iteration t: stage tile t+2 (6 gload_lds/wave) -> ds_read tile t
//     (16 x b128, swizzled) -> s_waitcnt vmcnt(6) -> s_barrier -> 32 MFMA
//     (setprio 1) -> s_barrier.  vmcnt(6) = the just-issued tile's 6 loads
//     may remain in flight; tile t+1's loads are thereby retired, and the
//     barrier makes that certification global. No vmcnt(0) in steady state.
//   - WAR on slots: stage target slot (t+2)%3 was last read at iter t-1,
//     whose reads complete before its end barrier (lgkm waits precede MFMA).
//   - T2: logical (row, 16B-block b) lives at LDS block (b ^ (row&7));
//     achieved by XORing the GLOBAL source address per lane (gload_lds dest
//     stays linear, rule 21) and XORing the ds_read address identically.
//     ds_read: lanes 0-15 hit 8 distinct 16B slots (2 lanes/bank = free).

#define DEV __device__ __forceinline__

typedef __bf16 bf16x8 __attribute__((ext_vector_type(8)));
typedef float  f32x4  __attribute__((ext_vector_type(4)));

static_assert(sizeof(bf16x8) == 16, "bf16x8 must be 16B");

DEV unsigned short f2bf(float f) {  // RTNE f32->bf16 (finite inputs)
  union { float f; unsigned u; } x; x.f = f;
  unsigned r = x.u + 0x7fffu + ((x.u >> 16) & 1u);
  return (unsigned short)(r >> 16);
}

DEV float sigm(float x) { return 1.f / (1.f + __expf(-x)); }

DEV void gload_lds16(const void* g, void* l) {
  // async global->LDS, 16B per lane; LDS dest is wave-uniform base + lane*16
  __builtin_amdgcn_global_load_lds(
      (__attribute__((address_space(1))) void*)(void*)g,
      (__attribute__((address_space(3))) void*)l, 16, 0, 0);
}

// ---------------- fused conversion kernel ----------------

struct CvtArgs {
  const float *data, *h_prev, *Wi, *Wh, *o_prev, *W_fb, *W_out;
  unsigned short *A_cat, *W_cat, *o_bf, *Wfb_bf, *Wout_bf;
};

DEV void cvt4(const float* src, unsigned short* dst) {
  float4 v = *reinterpret_cast<const float4*>(src);
  ushort4 o;
  o.x = f2bf(v.x); o.y = f2bf(v.y); o.z = f2bf(v.z); o.w = f2bf(v.w);
  *reinterpret_cast<ushort4*>(dst) = o;
}

__global__ __launch_bounds__(256)
void cvt_all_kernel(CvtArgs a) {
  const long t0 = 4096L * 3072 / 4;            // A_cat
  const long t1 = t0 + 8192L * 3072 / 4;       // W_cat
  const long t2 = t1 + 4096L * 2048 / 4;       // o_bf
  const long t3 = t2 + 2048L * 2048 / 4;       // Wfb_bf
  const long t4 = t3 + 2048L * 2048 / 4;       // Wout_bf
  long stride = (long)gridDim.x * blockDim.x;
  for (long g = (long)blockIdx.x * blockDim.x + threadIdx.x; g < t4; g += stride) {
    if (g < t0) {
      long e = g << 2;
      int col = (int)(e % 3072);
      long row = e / 3072;
      const float* src = (col < 1024) ? (a.data + row * 1024 + col)
                                      : (a.h_prev + row * 2048 + (col - 1024));
      cvt4(src, a.A_cat + e);
    } else if (g < t1) {
      long e = (g - t0) << 2;
      int col = (int)(e % 3072);
      long row = e / 3072;
      const float* src = (col < 1024) ? (a.Wi + row * 1024 + col)
                                      : (a.Wh + row * 2048 + (col - 1024));
      cvt4(src, a.W_cat + e);
    } else if (g < t2) {
      long e = (g - t1) << 2;
      cvt4(a.o_prev + e, a.o_bf + e);
    } else if (g < t3) {
      long e = (g - t2) << 2;
      cvt4(a.W_fb + e, a.Wfb_bf + e);
    } else {
      long e = (g - t3) << 2;
      cvt4(a.W_out + e, a.Wout_bf + e);
    }
  }
}

// ---------------- pipelined GEMM ----------------
// MODE 0: out[m,n] = sum_k A[m,k]*W[n,k] + bias[n]
// MODE 1: gates GEMM (logical N=8192). B-tile local row lr encodes
//         gate=(lr>>4)&3, h = bn*32 + (lr>>6)*16 + (lr&15); per-wave n-frag
//         ni == gate for fixed h = bn*32 + wn*16 + (l&15). Fused LSTM epilogue.

template<int MODE>
__global__ __launch_bounds__(512, 2)
void gemm3(const unsigned short* __restrict__ A,   // [M,K] bf16
           const unsigned short* __restrict__ W,   // [N,K] bf16
           const float* __restrict__ bias,
           float* __restrict__ out,
           const float* __restrict__ c_prev,
           const float* __restrict__ fb,
           float* __restrict__ out_h,
           float* __restrict__ out_c,
           unsigned short* __restrict__ h_bf,
           int M, int N, int K, int ntn) {
  // 3-slot LDS ring: A[256][64], B[128][64] bf16 per slot (48 KB); 144 KB total
  __shared__ unsigned short As[3][256 * 64];
  __shared__ unsigned short Bs[3][128 * 64];

  int nwg = gridDim.x;
  int wg = blockIdx.x;
  if ((nwg & 7) == 0) {                // XCD-aware swizzle (bijective: nwg%8==0)
    int q = nwg >> 3;
    wg = (wg & 7) * q + (wg >> 3);
  }
  int bm = wg / ntn, bn = wg % ntn;
  int m0 = bm * 256;

  int tid = threadIdx.x;
  int w = tid >> 6, l = tid & 63;
  int wm = w >> 1, wn = w & 1;         // 4 x 2 wave grid; per-wave 64x64 out

  // ---- staging descriptors --------------------------------------------
  // A: wave stages rows [wm*64 + wn*32, +32) as 4 instrs x 8 rows.
  // B: wave stages rows [wn*64 + wm*16, +16) as 2 instrs x 8 rows.
  // Within an instr: lane l -> local row base+ (l>>3), 16B-block (l&7).
  // T2 swizzle: LDS block (l&7) receives global block ((l&7) ^ (l>>3))
  // (row&7 == l>>3 since all row bases are multiples of 8).
  int lrow = l >> 3, lblk = l & 7;
  int gblk = lblk ^ lrow;              // swizzled global 16B-block
  int RaB = wm * 64 + wn * 32;
  int RbB = wn * 64 + wm * 16;

  size_t ga[4]; int aL[4];
#pragma unroll
  for (int j = 0; j < 4; ++j) {
    int r = RaB + j * 8 + lrow;                       // local row in [0,256)
    ga[j] = (size_t)(m0 + r) * K + (gblk << 3);       // element offset
    aL[j] = (RaB + j * 8) * 64;                       // wave-uniform LDS base
  }
  size_t gb[2]; int bL[2];
#pragma unroll
  for (int j = 0; j < 2; ++j) {
    int lr = RbB + j * 8 + lrow;                      // local row in [0,128)
    int grow;
    if (MODE == 0) grow = bn * 128 + lr;
    else grow = ((lr >> 4) & 3) * 2048 + bn * 32 + ((lr >> 6) << 4) + (lr & 15);
    gb[j] = (size_t)grow * K + (gblk << 3);
    bL[j] = (RbB + j * 8) * 64;
  }

#define STAGE_TILE(tt, s) do {                                   \
    const unsigned short* Ap_ = A + (size_t)(tt) * 64;           \
    const unsigned short* Wp_ = W + (size_t)(tt) * 64;           \
    _Pragma("unroll") for (int j_ = 0; j_ < 4; ++j_)             \
      gload_lds16(Ap_ + ga[j_], &As[s][aL[j_]]);                 \
    _Pragma("unroll") for (int j_ = 0; j_ < 2; ++j_)             \
      gload_lds16(Wp_ + gb[j_], &Bs[s][bL[j_]]);                 \
  } while (0)

  f32x4 acc[4][4];
#pragma unroll
  for (int i = 0; i < 4; ++i)
#pragma unroll
    for (int j = 0; j < 4; ++j) acc[i][j] = (f32x4){0.f, 0.f, 0.f, 0.f};

  int nt = K >> 6;

  // prologue: prime tiles 0,1; certify tile 0 (vmcnt(6) retires its 6 loads)
  STAGE_TILE(0, 0);
  STAGE_TILE(1, 1);
  asm volatile("s_waitcnt vmcnt(6)" ::: "memory");
  __builtin_amdgcn_s_barrier();

  int sRead = 0, sStage = 2;
  for (int t = 0; t < nt; ++t) {
    bool more = (t + 2) < nt;
    if (more) STAGE_TILE(t + 2, sStage);

    // ds_read 16 fragments of tile t (swizzled); issue before the wait
    bf16x8 af[2][4], bf[2][4];
#pragma unroll
    for (int ks = 0; ks < 2; ++ks) {
      int sw = ((ks << 2) + (l >> 4)) ^ (l & 7);      // row&7 == l&7 on reads
#pragma unroll
      for (int mi = 0; mi < 4; ++mi) {
        int r = wm * 64 + mi * 16 + (l & 15);
        af[ks][mi] = *reinterpret_cast<const bf16x8*>(&As[sRead][r * 64 + sw * 8]);
      }
#pragma unroll
      for (int ni = 0; ni < 4; ++ni) {
        int r = wn * 64 + ni * 16 + (l & 15);
        bf[ks][ni] = *reinterpret_cast<const bf16x8*>(&Bs[sRead][r * 64 + sw * 8]);
      }
    }

    // retire tile t+1's loads (keep tile t+2's 6 in flight); certify globally
    if (more) asm volatile("s_waitcnt vmcnt(6)" ::: "memory");
    else      asm volatile("s_waitcnt vmcnt(0)" ::: "memory");
    __builtin_amdgcn_s_barrier();

    __builtin_amdgcn_s_setprio(1);
#pragma unroll
    for (int ks = 0; ks < 2; ++ks)
#pragma unroll
      for (int mi = 0; mi < 4; ++mi)
#pragma unroll
        for (int ni = 0; ni < 4; ++ni)
          acc[mi][ni] = __builtin_amdgcn_mfma_f32_16x16x32_bf16(
              af[ks][mi], bf[ks][ni], acc[mi][ni], 0, 0, 0);
    __builtin_amdgcn_s_setprio(0);
    __builtin_amdgcn_s_barrier();   // reads of sRead done -> next stage may reuse

    sRead = (sRead == 2) ? 0 : sRead + 1;
    sStage = (sStage == 2) ? 0 : sStage + 1;
  }
#undef STAGE_TILE

  if (MODE == 0) {
#pragma unroll
    for (int mi = 0; mi < 4; ++mi) {
#pragma unroll
      for (int r = 0; r < 4; ++r) {
        int m = m0 + wm * 64 + mi * 16 + ((l >> 4) << 2) + r;
#pragma unroll
        for (int ni = 0; ni < 4; ++ni) {
          int n = bn * 128 + wn * 64 + ni * 16 + (l & 15);
          out[(size_t)m * N + n] = acc[mi][ni][r] + bias[n];
        }
      }
    }
  } else {
    int h = bn * 32 + wn * 16 + (l & 15);
    float bii = bias[h], bif = bias[2048 + h], big = bias[4096 + h], bio = bias[6144 + h];
#pragma unroll
    for (int mi = 0; mi < 4; ++mi) {
#pragma unroll
      for (int r = 0; r < 4; ++r) {
        int m = m0 + wm * 64 + mi * 16 + ((l >> 4) << 2) + r;
        size_t idx = (size_t)m * 2048 + h;
        float iv = sigm(acc[mi][0][r] + bii);
        float fv = sigm(acc[mi][1][r] + bif);
        float gv = tanhf(acc[mi][2][r] + big);
        float ov = sigm(acc[mi][3][r] + bio);
        float c = fv * c_prev[idx] + iv * gv + fb[idx];
        float ht = ov * tanhf(c);
        out_c[idx] = c;
        out_h[idx] = ht;
        h_bf[idx] = f2bf(ht);
      }
    }
  }
}

// ---------------- softmax ----------------

__global__ __launch_bounds__(256)
void softmax_kernel(const float* __restrict__ logits, float* __restrict__ out) {
  int row = blockIdx.x;
  int tid = threadIdx.x;
  const float* x = logits + (size_t)row * 2048;
  float4 v0 = *reinterpret_cast<const float4*>(x + tid * 4);
  float4 v1 = *reinterpret_cast<const float4*>(x + 1024 + tid * 4);
  float mx = fmaxf(fmaxf(fmaxf(v0.x, v0.y), fmaxf(v0.z, v0.w)),
                   fmaxf(fmaxf(v1.x, v1.y), fmaxf(v1.z, v1.w)));
#pragma unroll
  for (int o = 32; o; o >>= 1) mx = fmaxf(mx, __shfl_xor(mx, o));
  __shared__ float redm[4], reds[4];
  int w = tid >> 6, l = tid & 63;
  if (l == 0) redm[w] = mx;
  __syncthreads();
  mx = fmaxf(fmaxf(redm[0], redm[1]), fmaxf(redm[2], redm[3]));
  float e[8];
  e[0] = __expf(v0.x - mx); e[1] = __expf(v0.y - mx);
  e[2] = __expf(v0.z - mx); e[3] = __expf(v0.w - mx);
  e[4] = __expf(v1.x - mx); e[5] = __expf(v1.y - mx);
  e[6] = __expf(v1.z - mx); e[7] = __expf(v1.w - mx);
  float s = ((e[0] + e[1]) + (e[2] + e[3])) + ((e[4] + e[5]) + (e[6] + e[7]));
#pragma unroll
  for (int o = 32; o; o >>= 1) s += __shfl_xor(s, o);
  if (l == 0) reds[w] = s;
  __syncthreads();
  s = reds[0] + reds[1] + reds[2] + reds[3];
  float inv = 1.f / s;
  float4 o0, o1;
  o0.x = e[0] * inv; o0.y = e[1] * inv; o0.z = e[2] * inv; o0.w = e[3] * inv;
  o1.x = e[4] * inv; o1.y = e[5] * inv; o1.z = e[6] * inv; o1.w = e[7] * inv;
  float* y = out + (size_t)row * 2048;
  *reinterpret_cast<float4*>(y + tid * 4) = o0;
  *reinterpret_cast<float4*>(y + 1024 + tid * 4) = o1;
}

// ---------------- launch ----------------

extern "C" void kernel_launch(void* const* d_in, const int* in_sizes, int n_in,
                              void* d_out, int out_size, void* d_ws, size_t ws_size,
                              hipStream_t stream) {
  const float* data   = (const float*)d_in[0];
  const float* h_prev = (const float*)d_in[1];
  const float* c_prev = (const float*)d_in[2];
  const float* o_prev = (const float*)d_in[3];
  const float* Wi     = (const float*)d_in[4];
  const float* bi     = (const float*)d_in[5];
  const float* Wh     = (const float*)d_in[6];
  const float* W_out  = (const float*)d_in[7];
  const float* b_out  = (const float*)d_in[8];
  const float* W_fb   = (const float*)d_in[9];
  const float* b_fb   = (const float*)d_in[10];

  constexpr int B = 4096, H = 2048, O = 2048;
  constexpr size_t BH = (size_t)B * H;

  char* ws = (char*)d_ws;
  unsigned short* A_cat  = (unsigned short*)ws; ws += (size_t)B * 3072 * 2;      // 25.2 MB
  unsigned short* W_cat  = (unsigned short*)ws; ws += (size_t)4 * H * 3072 * 2;  // 50.3 MB
  unsigned short* o_bf   = (unsigned short*)ws; ws += BH * 2;                    // 16.8 MB
  unsigned short* Wfb_bf = (unsigned short*)ws; ws += (size_t)H * H * 2;         //  8.4 MB
  unsigned short* Wout_bf= (unsigned short*)ws; ws += (size_t)O * H * 2;         //  8.4 MB
  float*          fb_f   = (float*)ws;          ws += BH * 4;                    // 33.6 MB (reused for logits)
  // h_bf ALIASES o_bf: fb GEMM's reads of o_bf complete (stream order) before
  // the gates GEMM writes h_bf.
  unsigned short* h_bf   = o_bf;

  float* out_p = (float*)d_out;            // softmax output [B,O]
  float* out_h = out_p + (size_t)B * O;    // h_t [B,H]
  float* out_c = out_h + BH;               // c_t [B,H]

  CvtArgs ca;
  ca.data = data; ca.h_prev = h_prev; ca.Wi = Wi; ca.Wh = Wh;
  ca.o_prev = o_prev; ca.W_fb = W_fb; ca.W_out = W_out;
  ca.A_cat = A_cat; ca.W_cat = W_cat; ca.o_bf = o_bf;
  ca.Wfb_bf = Wfb_bf; ca.Wout_bf = Wout_bf;
  cvt_all_kernel<<<2048, 256, 0, stream>>>(ca);

  // fb = o_prev @ W_fb^T + b_fb        (grid 16x16 = 256, %8==0)
  gemm3<0><<<(B / 256) * (H / 128), 512, 0, stream>>>(
      o_bf, Wfb_bf, b_fb, fb_f, nullptr, nullptr, nullptr, nullptr, nullptr,
      B, H, H, H / 128);
  // gates (fused LSTM epilogue)       (grid 16x64 = 1024, %8==0)
  gemm3<1><<<(B / 256) * (4 * H / 128), 512, 0, stream>>>(
      A_cat, W_cat, bi, nullptr, c_prev, fb_f, out_h, out_c, h_bf,
      B, 4 * H, 3072, (4 * H) / 128);
  // logits = h_t @ W_out^T + b_out    (into fb_f, no longer needed)
  gemm3<0><<<(B / 256) * (O / 128), 512, 0, stream>>>(
      h_bf, Wout_bf, b_out, fb_f, nullptr, nullptr, nullptr, nullptr, nullptr,
      B, O, H, O / 128);
  softmax_kernel<<<B, 256, 0, stream>>>(fb_f, out_p);
}

// Round 6
// 651.854 us; speedup vs baseline: 1.2054x; 1.2054x over previous
//
#include <hip/hip_runtime.h>
#include <hip/hip_bf16.h>

// LSTM cell fused pipeline for MI355X (gfx950).
// B=4096, D=1024, H=2048, O=2048, all f32 in/out; GEMMs in bf16 MFMA.
//
// Round-5: gates GEMM moved to a proven-accounting 8-phase pipelined kernel
// (gemm8p): 256x256 tile, BK=64, 8 waves (2M x 4N, per-wave 128x64 out),
// LDS 128KB = 2 dbuf x 2 halves x [128][64] for A and B, T2 XOR-swizzle,
// counted vmcnt(6) once per K-tile (3 half-tiles in flight), 16-MFMA phases
// with setprio. fb/logits GEMMs use the r4-proven 2-barrier 128^2 gemm_bt.
//
// gemm8p schedule per K-tile g (buf = g&1), 4 phases:
//  P1: ds_read A-half0 frags (8 x b128) + B-half0 frags (4) ;
//      stage [g+1.A1] (2 gloads) ; barrier ; 16 MFMA (acc[0..3][0..1]) ; barrier
//  P2: ds_read B-half1 (4) ; stage [g+2.A0] ; barrier ; 16 MFMA [0..3][2..3] ; barrier
//  P3: ds_read A-half1 (8) ; stage [g+2.B0] ; barrier ; 16 MFMA [4..7][0..1] ; barrier
//  P4: stage [g+2.B1] ; s_waitcnt vmcnt(6) ; barrier ; 16 MFMA [4..7][2..3] ; barrier
// Proofs: WAR - each stage's target slot was fully read in an earlier phase
// (A0,B0 @P1, B1 @P2, A1 @P3; b-frags persist in regs so P3/P4 never re-read
// B0/B1 from LDS). RAW - K-tile j's halves staged at (j-2).P2..P4 and (j-1).P1
// are all retired by (j-1).P4's vmcnt(6) (outstanding = (j-1).P2..P4's 6
// loads) and certified by the barrier that follows it.

#define DEV __device__ __forceinline__

typedef __bf16 bf16x8 __attribute__((ext_vector_type(8)));
typedef float  f32x4  __attribute__((ext_vector_type(4)));

static_assert(sizeof(bf16x8) == 16, "bf16x8 must be 16B");

DEV unsigned short f2bf(float f) {  // RTNE f32->bf16 (finite inputs)
  union { float f; unsigned u; } x; x.f = f;
  unsigned r = x.u + 0x7fffu + ((x.u >> 16) & 1u);
  return (unsigned short)(r >> 16);
}

DEV float sigm(float x) { return 1.f / (1.f + __expf(-x)); }

DEV void gload_lds16(const void* g, void* l) {
  __builtin_amdgcn_global_load_lds(
      (__attribute__((address_space(1))) void*)(void*)g,
      (__attribute__((address_space(3))) void*)l, 16, 0, 0);
}

// ---------------- fused conversion kernel ----------------

struct CvtArgs {
  const float *data, *h_prev, *Wi, *Wh, *o_prev, *W_fb, *W_out;
  unsigned short *A_cat, *W_cat, *o_bf, *Wfb_bf, *Wout_bf;
};

DEV void cvt4(const float* src, unsigned short* dst) {
  float4 v = *reinterpret_cast<const float4*>(src);
  ushort4 o;
  o.x = f2bf(v.x); o.y = f2bf(v.y); o.z = f2bf(v.z); o.w = f2bf(v.w);
  *reinterpret_cast<ushort4*>(dst) = o;
}

__global__ __launch_bounds__(256)
void cvt_all_kernel(CvtArgs a) {
  const long t0 = 4096L * 3072 / 4;
  const long t1 = t0 + 8192L * 3072 / 4;
  const long t2 = t1 + 4096L * 2048 / 4;
  const long t3 = t2 + 2048L * 2048 / 4;
  const long t4 = t3 + 2048L * 2048 / 4;
  long stride = (long)gridDim.x * blockDim.x;
  for (long g = (long)blockIdx.x * blockDim.x + threadIdx.x; g < t4; g += stride) {
    if (g < t0) {
      long e = g << 2; int col = (int)(e % 3072); long row = e / 3072;
      const float* src = (col < 1024) ? (a.data + row * 1024 + col)
                                      : (a.h_prev + row * 2048 + (col - 1024));
      cvt4(src, a.A_cat + e);
    } else if (g < t1) {
      long e = (g - t0) << 2; int col = (int)(e % 3072); long row = e / 3072;
      const float* src = (col < 1024) ? (a.Wi + row * 1024 + col)
                                      : (a.Wh + row * 2048 + (col - 1024));
      cvt4(src, a.W_cat + e);
    } else if (g < t2) { long e = (g - t1) << 2; cvt4(a.o_prev + e, a.o_bf + e); }
    else if (g < t3)   { long e = (g - t2) << 2; cvt4(a.W_fb + e, a.Wfb_bf + e); }
    else               { long e = (g - t3) << 2; cvt4(a.W_out + e, a.Wout_bf + e); }
  }
}

// ---------------- 8-phase pipelined gates GEMM ----------------
// A_cat [4096,3072], W_cat [8192,3072] with gate-interleaved B-tile rows:
// tile-local B row lr (0..255): gate = ((lr>>4)&1) + 2*((lr>>7)&1),
// W row = gate*2048 + bn*64 + ((lr>>5)&3)*16 + (lr&15).
// Per-wave (wm in 0..1, wn in 0..3): out rows (mi>>2)*128 + wm*64 + (mi&3)*16,
// cols (ni>>1)*128 + wn*32 + (ni&1)*16 -> gate = ni at h = bn*64+wn*16+(l&15).

#define MMA_PHASE(AF, BF, MB, NB)                                        \
  __builtin_amdgcn_s_setprio(1);                                         \
  _Pragma("unroll") for (int ks_ = 0; ks_ < 2; ++ks_)                    \
  _Pragma("unroll") for (int i_ = 0; i_ < 4; ++i_)                       \
  _Pragma("unroll") for (int j_ = 0; j_ < 2; ++j_)                       \
    acc[MB + i_][NB + j_] = __builtin_amdgcn_mfma_f32_16x16x32_bf16(     \
        AF[i_][ks_], BF[j_][ks_], acc[MB + i_][NB + j_], 0, 0, 0);       \
  __builtin_amdgcn_s_setprio(0);

__global__ __launch_bounds__(512, 2)
void gemm8p(const unsigned short* __restrict__ A,   // [4096,K] bf16
            const unsigned short* __restrict__ W,   // [8192,K] bf16 (gates)
            const float* __restrict__ bias,         // [8192]
            const float* __restrict__ c_prev,
            const float* __restrict__ fb,
            float* __restrict__ out_h,
            float* __restrict__ out_c,
            unsigned short* __restrict__ h_bf,
            int K, int ntn) {
  // [buf][half][128][64] for each of A,B : 32768 shorts = 64KB each
  __shared__ unsigned short As[2 * 2 * 128 * 64];
  __shared__ unsigned short Bs[2 * 2 * 128 * 64];

  int nwg = gridDim.x;
  int wg = blockIdx.x;
  { int q = nwg >> 3; wg = (wg & 7) * q + (wg >> 3); }  // nwg % 8 == 0
  int bm = wg / ntn, bn = wg % ntn;
  int m0 = bm * 256;

  int tid = threadIdx.x;
  int w = tid >> 6, l = tid & 63;
  int wm = w >> 2, wn = w & 3;

  // staging descriptors: half-tile = 128 rows x 64 k (16KB) = 16 chunks of
  // 8 rows; wave w owns chunks w*2+j. lane l -> row +(l>>3), 16B-block (l&7).
  // T2: LDS stays linear; global source block is pre-swizzled (^ row&7).
  int lrow = l >> 3;
  int gblk = (l & 7) ^ lrow;
  size_t gA[2][2], gB[2][2];
  int    lL[2][2];
#pragma unroll
  for (int h = 0; h < 2; ++h)
#pragma unroll
    for (int j = 0; j < 2; ++j) {
      int c = w * 2 + j;
      int lr = h * 128 + c * 8 + lrow;          // tile-local row 0..255
      gA[h][j] = (size_t)(m0 + lr) * K + gblk * 8;
      int gate = ((lr >> 4) & 1) + 2 * ((lr >> 7) & 1);
      int grow = gate * 2048 + bn * 64 + ((lr >> 5) & 3) * 16 + (lr & 15);
      gB[h][j] = (size_t)grow * K + gblk * 8;
      lL[h][j] = (h * 128 + c * 8) * 64;        // wave-uniform LDS elem base
    }

  auto stageA = [&](int t, int h) {
#pragma unroll
    for (int j = 0; j < 2; ++j)
      gload_lds16(A + gA[h][j] + (size_t)t * 64, &As[(t & 1) * 16384 + lL[h][j]]);
  };
  auto stageB = [&](int t, int h) {
#pragma unroll
    for (int j = 0; j < 2; ++j)
      gload_lds16(W + gB[h][j] + (size_t)t * 64, &Bs[(t & 1) * 16384 + lL[h][j]]);
  };

  f32x4 acc[8][4];
#pragma unroll
  for (int i = 0; i < 8; ++i)
#pragma unroll
    for (int j = 0; j < 4; ++j) acc[i][j] = (f32x4){0.f, 0.f, 0.f, 0.f};

  bf16x8 af[4][2], b0[2][2], b1[2][2];
  int nt = K >> 6;

  // prologue: K0 fully (8 loads), K1 halves A0,B0,B1 (6 loads)
  stageA(0, 0); stageB(0, 0); stageB(0, 1); stageA(0, 1);
  stageA(1, 0); stageB(1, 0); stageB(1, 1);
  asm volatile("s_waitcnt vmcnt(6)" ::: "memory");   // K0 resident
  __builtin_amdgcn_s_barrier();

#pragma unroll 1
  for (int g0 = 0; g0 < nt; g0 += 2) {
#pragma unroll
    for (int bb = 0; bb < 2; ++bb) {       // bb == buf (literal after unroll)
      const int g = g0 + bb;
      // ---- P1: A-half0 (8 reads) + B-half0 (4 reads) ----
#pragma unroll
      for (int i = 0; i < 4; ++i) {
        int row = wm * 64 + i * 16 + (l & 15);
#pragma unroll
        for (int ks = 0; ks < 2; ++ks) {
          int blk = (ks * 4 + (l >> 4)) ^ (l & 7);
          af[i][ks] = *reinterpret_cast<const bf16x8*>(
              &As[bb * 16384 + 0 * 8192 + row * 64 + blk * 8]);
        }
      }
#pragma unroll
      for (int j = 0; j < 2; ++j) {
        int row = wn * 32 + j * 16 + (l & 15);
#pragma unroll
        for (int ks = 0; ks < 2; ++ks) {
          int blk = (ks * 4 + (l >> 4)) ^ (l & 7);
          b0[j][ks] = *reinterpret_cast<const bf16x8*>(
              &Bs[bb * 16384 + 0 * 8192 + row * 64 + blk * 8]);
        }
      }
      if (g + 1 < nt) stageA(g + 1, 1);
      __builtin_amdgcn_s_barrier();
      MMA_PHASE(af, b0, 0, 0);
      __builtin_amdgcn_s_barrier();
      // ---- P2: B-half1 (4 reads) ----
#pragma unroll
      for (int j = 0; j < 2; ++j) {
        int row = wn * 32 + j * 16 + (l & 15);
#pragma unroll
        for (int ks = 0; ks < 2; ++ks) {
          int blk = (ks * 4 + (l >> 4)) ^ (l & 7);
          b1[j][ks] = *reinterpret_cast<const bf16x8*>(
              &Bs[bb * 16384 + 1 * 8192 + row * 64 + blk * 8]);
        }
      }
      if (g + 2 < nt) stageA(g + 2, 0);
      __builtin_amdgcn_s_barrier();
      MMA_PHASE(af, b1, 0, 2);
      __builtin_amdgcn_s_barrier();
      // ---- P3: A-half1 (8 reads) ----
#pragma unroll
      for (int i = 0; i < 4; ++i) {
        int row = wm * 64 + i * 16 + (l & 15);
#pragma unroll
        for (int ks = 0; ks < 2; ++ks) {
          int blk = (ks * 4 + (l >> 4)) ^ (l & 7);
          af[i][ks] = *reinterpret_cast<const bf16x8*>(
              &As[bb * 16384 + 1 * 8192 + row * 64 + blk * 8]);
        }
      }
      if (g + 2 < nt) stageB(g + 2, 0);
      __builtin_amdgcn_s_barrier();
      MMA_PHASE(af, b0, 4, 0);
      __builtin_amdgcn_s_barrier();
      // ---- P4: no reads ----
      if (g + 2 < nt) {
        stageB(g + 2, 1);
        asm volatile("s_waitcnt vmcnt(6)" ::: "memory");
      } else {
        asm volatile("s_waitcnt vmcnt(0)" ::: "memory");
      }
      __builtin_amdgcn_s_barrier();
      MMA_PHASE(af, b1, 4, 2);
      __builtin_amdgcn_s_barrier();
    }
  }

  // ---- fused LSTM epilogue ----
  int h = bn * 64 + wn * 16 + (l & 15);
  float bii = bias[h], bif = bias[2048 + h], big = bias[4096 + h], bio = bias[6144 + h];
#pragma unroll
  for (int mi = 0; mi < 8; ++mi) {
#pragma unroll
    for (int r = 0; r < 4; ++r) {
      int m = m0 + (mi >> 2) * 128 + wm * 64 + (mi & 3) * 16 + ((l >> 4) << 2) + r;
      size_t idx = (size_t)m * 2048 + h;
      float iv = sigm(acc[mi][0][r] + bii);
      float fv = sigm(acc[mi][1][r] + bif);
      float gv = tanhf(acc[mi][2][r] + big);
      float ov = sigm(acc[mi][3][r] + bio);
      float c = fv * c_prev[idx] + iv * gv + fb[idx];
      float ht = ov * tanhf(c);
      out_c[idx] = c;
      out_h[idx] = ht;
      h_bf[idx] = f2bf(ht);
    }
  }
}

// ---------------- r4-proven 2-barrier 128^2 GEMM (fb, logits) ----------------

__global__ __launch_bounds__(256, 2)
void gemm_bt(const unsigned short* __restrict__ A,   // [M,K] bf16
             const unsigned short* __restrict__ W,   // [N,K] bf16
             const float* __restrict__ bias,
             float* __restrict__ out,
             int M, int N, int K, int ntn) {
  __shared__ unsigned short As[128 * 64];
  __shared__ unsigned short Bs[128 * 64];

  int nwg = gridDim.x;
  int wg = blockIdx.x;
  if ((nwg & 7) == 0) { int q = nwg >> 3; wg = (wg & 7) * q + (wg >> 3); }
  int bm = wg / ntn, bn = wg % ntn;
  int m0 = bm * 128;

  int tid = threadIdx.x;
  int w = tid >> 6, l = tid & 63;
  int wr = w >> 1, wc = w & 1;

  size_t goffA[4], goffB[4];
#pragma unroll
  for (int j = 0; j < 4; ++j) {
    int c = w * 4 + j;
    int lr = c * 8 + (l >> 3);
    int kk = (l & 7) * 8;
    goffA[j] = (size_t)(m0 + lr) * K + kk;
    goffB[j] = (size_t)(bn * 128 + lr) * K + kk;
  }

  f32x4 acc[4][4];
#pragma unroll
  for (int i = 0; i < 4; ++i)
#pragma unroll
    for (int j = 0; j < 4; ++j) acc[i][j] = (f32x4){0.f, 0.f, 0.f, 0.f};

  int arow = wr * 64 + (l & 15);
  int brow = wc * 64 + (l & 15);
  int kfrag = (l >> 4) * 8;

  for (int k0 = 0; k0 < K; k0 += 64) {
#pragma unroll
    for (int j = 0; j < 4; ++j) {
      gload_lds16(A + goffA[j] + k0, &As[(w * 4 + j) * 512]);
      gload_lds16(W + goffB[j] + k0, &Bs[(w * 4 + j) * 512]);
    }
    __syncthreads();
#pragma unroll
    for (int ks = 0; ks < 2; ++ks) {
      bf16x8 a[4], b[4];
#pragma unroll
      for (int mi = 0; mi < 4; ++mi)
        a[mi] = *reinterpret_cast<const bf16x8*>(&As[(arow + mi * 16) * 64 + ks * 32 + kfrag]);
#pragma unroll
      for (int ni = 0; ni < 4; ++ni)
        b[ni] = *reinterpret_cast<const bf16x8*>(&Bs[(brow + ni * 16) * 64 + ks * 32 + kfrag]);
#pragma unroll
      for (int mi = 0; mi < 4; ++mi)
#pragma unroll
        for (int ni = 0; ni < 4; ++ni)
          acc[mi][ni] = __builtin_amdgcn_mfma_f32_16x16x32_bf16(a[mi], b[ni], acc[mi][ni], 0, 0, 0);
    }
    __syncthreads();
  }

#pragma unroll
  for (int mi = 0; mi < 4; ++mi) {
#pragma unroll
    for (int r = 0; r < 4; ++r) {
      int m = m0 + wr * 64 + mi * 16 + ((l >> 4) << 2) + r;
#pragma unroll
      for (int ni = 0; ni < 4; ++ni) {
        int n = bn * 128 + wc * 64 + ni * 16 + (l & 15);
        out[(size_t)m * N + n] = acc[mi][ni][r] + bias[n];
      }
    }
  }
}

// ---------------- softmax ----------------

__global__ __launch_bounds__(256)
void softmax_kernel(const float* __restrict__ logits, float* __restrict__ out) {
  int row = blockIdx.x;
  int tid = threadIdx.x;
  const float* x = logits + (size_t)row * 2048;
  float4 v0 = *reinterpret_cast<const float4*>(x + tid * 4);
  float4 v1 = *reinterpret_cast<const float4*>(x + 1024 + tid * 4);
  float mx = fmaxf(fmaxf(fmaxf(v0.x, v0.y), fmaxf(v0.z, v0.w)),
                   fmaxf(fmaxf(v1.x, v1.y), fmaxf(v1.z, v1.w)));
#pragma unroll
  for (int o = 32; o; o >>= 1) mx = fmaxf(mx, __shfl_xor(mx, o));
  __shared__ float redm[4], reds[4];
  int w = tid >> 6, l = tid & 63;
  if (l == 0) redm[w] = mx;
  __syncthreads();
  mx = fmaxf(fmaxf(redm[0], redm[1]), fmaxf(redm[2], redm[3]));
  float e[8];
  e[0] = __expf(v0.x - mx); e[1] = __expf(v0.y - mx);
  e[2] = __expf(v0.z - mx); e[3] = __expf(v0.w - mx);
  e[4] = __expf(v1.x - mx); e[5] = __expf(v1.y - mx);
  e[6] = __expf(v1.z - mx); e[7] = __expf(v1.w - mx);
  float s = ((e[0] + e[1]) + (e[2] + e[3])) + ((e[4] + e[5]) + (e[6] + e[7]));
#pragma unroll
  for (int o = 32; o; o >>= 1) s += __shfl_xor(s, o);
  if (l == 0) reds[w] = s;
  __syncthreads();
  s = reds[0] + reds[1] + reds[2] + reds[3];
  float inv = 1.f / s;
  float4 o0, o1;
  o0.x = e[0] * inv; o0.y = e[1] * inv; o0.z = e[2] * inv; o0.w = e[3] * inv;
  o1.x = e[4] * inv; o1.y = e[5] * inv; o1.z = e[6] * inv; o1.w = e[7] * inv;
  float* y = out + (size_t)row * 2048;
  *reinterpret_cast<float4*>(y + tid * 4) = o0;
  *reinterpret_cast<float4*>(y + 1024 + tid * 4) = o1;
}

// ---------------- launch ----------------

extern "C" void kernel_launch(void* const* d_in, const int* in_sizes, int n_in,
                              void* d_out, int out_size, void* d_ws, size_t ws_size,
                              hipStream_t stream) {
  const float* data   = (const float*)d_in[0];
  const float* h_prev = (const float*)d_in[1];
  const float* c_prev = (const float*)d_in[2];
  const float* o_prev = (const float*)d_in[3];
  const float* Wi     = (const float*)d_in[4];
  const float* bi     = (const float*)d_in[5];
  const float* Wh     = (const float*)d_in[6];
  const float* W_out  = (const float*)d_in[7];
  const float* b_out  = (const float*)d_in[8];
  const float* W_fb   = (const float*)d_in[9];
  const float* b_fb   = (const float*)d_in[10];

  constexpr int B = 4096, H = 2048, O = 2048;
  constexpr size_t BH = (size_t)B * H;

  char* ws = (char*)d_ws;
  unsigned short* A_cat  = (unsigned short*)ws; ws += (size_t)B * 3072 * 2;
  unsigned short* W_cat  = (unsigned short*)ws; ws += (size_t)4 * H * 3072 * 2;
  unsigned short* o_bf   = (unsigned short*)ws; ws += BH * 2;
  unsigned short* Wfb_bf = (unsigned short*)ws; ws += (size_t)H * H * 2;
  unsigned short* Wout_bf= (unsigned short*)ws; ws += (size_t)O * H * 2;
  float*          fb_f   = (float*)ws;          ws += BH * 4;
  unsigned short* h_bf   = o_bf;   // alias: o_bf reads finish before h_bf writes

  float* out_p = (float*)d_out;
  float* out_h = out_p + (size_t)B * O;
  float* out_c = out_h + BH;

  CvtArgs ca;
  ca.data = data; ca.h_prev = h_prev; ca.Wi = Wi; ca.Wh = Wh;
  ca.o_prev = o_prev; ca.W_fb = W_fb; ca.W_out = W_out;
  ca.A_cat = A_cat; ca.W_cat = W_cat; ca.o_bf = o_bf;
  ca.Wfb_bf = Wfb_bf; ca.Wout_bf = Wout_bf;
  cvt_all_kernel<<<2048, 256, 0, stream>>>(ca);

  // fb = o_prev @ W_fb^T + b_fb          (grid 32x16 = 512)
  gemm_bt<<<(B / 128) * (H / 128), 256, 0, stream>>>(
      o_bf, Wfb_bf, b_fb, fb_f, B, H, H, H / 128);
  // gates, 8-phase pipelined + fused LSTM epilogue  (grid 16x32 = 512)
  gemm8p<<<(B / 256) * (4 * H / 256), 512, 0, stream>>>(
      A_cat, W_cat, bi, c_prev, fb_f, out_h, out_c, h_bf, 3072, (4 * H) / 256);
  // logits = h_t @ W_out^T + b_out       (grid 32x16 = 512)
  gemm_bt<<<(B / 128) * (O / 128), 256, 0, stream>>>(
      h_bf, Wout_bf, b_out, fb_f, B, O, H, O / 128);
  softmax_kernel<<<B, 256, 0, stream>>>(fb_f, out_p);
}